// Round 6
// baseline (501.691 us; speedup 1.0000x reference)
//
#include <hip/hip_runtime.h>
#include <stdint.h>
#include <math.h>

// FuXi block on MI355X, round 6: occupancy round.
// - QKVU fused GEMM (N=4096, per-block bias/act select), tiles 128x64 -> 2-8 blocks/CU
// - attention: 64-row Q blocks (grid 1024), double-buffered LDS, 1 barrier/iter
// - activations in one [4096][4096] QKVU buffer (ld=4096 views); ws = 56 MB.

#define D    1024
#define NH   16
#define DH   64
#define B_   2
#define S_   2048
#define ROWS 4096
#define LQ   4096          // QKVU row stride
#define EPSR 1e-8f

typedef unsigned short u16;
typedef __attribute__((ext_vector_type(8))) short short8;
typedef __attribute__((ext_vector_type(4))) float f32x4;

__device__ __forceinline__ float bf2f(u16 u) {
    union { uint32_t i; float f; } c; c.i = ((uint32_t)u) << 16; return c.f;
}
__device__ __forceinline__ u16 f2bf(float f) {
    union { float f; uint32_t i; } c; c.f = f;
    uint32_t x = c.i;
    x += 0x7fffu + ((x >> 16) & 1u);
    return (u16)(x >> 16);
}
__device__ __forceinline__ float silu_f(float v) { return v / (1.0f + __expf(-v)); }

// ---------------- weight prep: fp32 W[K=1024][N] -> bf16 WT[N][1024] ----------------
__global__ __launch_bounds__(256) void transpose_cast_kernel(
    const float* __restrict__ W, u16* __restrict__ WTo, int N)
{
    __shared__ float T[64][65];
    const int tid = threadIdx.x;
    const int n0 = blockIdx.x << 6;
    const int k0 = blockIdx.y << 6;
    const int rr = tid >> 4;
    const int cc = (tid & 15) << 2;
#pragma unroll
    for (int l = 0; l < 4; ++l) {
        const int r = rr + (l << 4);
        float4 v = *(const float4*)&W[(size_t)(k0 + r) * N + n0 + cc];
        T[cc + 0][r] = v.x; T[cc + 1][r] = v.y;
        T[cc + 2][r] = v.z; T[cc + 3][r] = v.w;
    }
    __syncthreads();
    const int n  = tid >> 2;
    const int ks = (tid & 3) << 4;
#pragma unroll
    for (int m = 0; m < 4; ++m) {
        const int k = ks + (m << 2);
        float4 v = *(const float4*)&T[n][k];
        ushort4 o;
        o.x = f2bf(v.x); o.y = f2bf(v.y); o.z = f2bf(v.z); o.w = f2bf(v.w);
        *(ushort4*)&WTo[(size_t)(n0 + n) * 1024 + k0 + k] = o;
    }
}

// ---------------- RMSNorm: strided in (fp32 or bf16), strided bf16 mul, strided bf16 out ----
__global__ __launch_bounds__(256) void rmsnorm_kernel(
    const float* __restrict__ inf, const u16* __restrict__ inb, int ldi,
    const float* __restrict__ g,
    const u16* __restrict__ mul, int ldm,
    u16* __restrict__ out, int ldo)
{
    const int row = blockIdx.x;
    const int tid = threadIdx.x;
    const int c = tid << 2;
    float x0, x1, x2, x3;
    if (inb) {
        ushort4 xi = *(const ushort4*)&inb[(size_t)row * ldi + c];
        x0 = bf2f(xi.x); x1 = bf2f(xi.y); x2 = bf2f(xi.z); x3 = bf2f(xi.w);
    } else {
        float4 xi = *(const float4*)&inf[(size_t)row * ldi + c];
        x0 = xi.x; x1 = xi.y; x2 = xi.z; x3 = xi.w;
    }
    float ss = x0*x0 + x1*x1 + x2*x2 + x3*x3;
#pragma unroll
    for (int off = 32; off > 0; off >>= 1) ss += __shfl_down(ss, off, 64);
    __shared__ float red[4];
    if ((tid & 63) == 0) red[tid >> 6] = ss;
    __syncthreads();
    float r = rsqrtf((red[0] + red[1] + red[2] + red[3]) * (1.0f / D) + EPSR);
    float4 gv = *(const float4*)&g[c];
    float v0 = x0 * r * gv.x, v1 = x1 * r * gv.y, v2 = x2 * r * gv.z, v3 = x3 * r * gv.w;
    if (mul) {
        ushort4 mi = *(const ushort4*)&mul[(size_t)row * ldm + c];
        v0 *= bf2f(mi.x); v1 *= bf2f(mi.y); v2 *= bf2f(mi.z); v3 *= bf2f(mi.w);
    }
    ushort4 o;
    o.x = f2bf(v0); o.y = f2bf(v1); o.z = f2bf(v2); o.w = f2bf(v3);
    *(ushort4*)&out[(size_t)row * ldo + c] = o;
}

// ---------------- MFMA GEMM: C[4096,N] = A[4096,1024](bf16,lda) @ WT^T ----------------
// Tile 128x64, 4 waves as 2x2 (each 64x32), BK=32, global_load_lds w=16.
// Bias/act selected per 1024-col chunk (sel = col0>>10, block-uniform):
// bias = bsel[colg&1023], act = (actmask>>sel)&1. Optional fp32 res/out (ldo must
// be 1024 for res/outf). res may alias outf.
__global__ __launch_bounds__(256) void gemm_mfma(
    const u16* __restrict__ A, int lda, const u16* __restrict__ WT,
    const float* __restrict__ bs0, const float* __restrict__ bs1,
    const float* __restrict__ bs2, const float* __restrict__ bs3,
    const float* __restrict__ res,
    u16* __restrict__ outb, float* __restrict__ outf,
    int ldo, int actmask)
{
    __shared__ u16 As[128 * 32];
    __shared__ u16 Bs[64 * 32];
    const int tid  = threadIdx.x;
    const int wave = tid >> 6;
    const int lane = tid & 63;
    const int lm   = lane & 15;
    const int quad = lane >> 4;
    const int row0 = blockIdx.y << 7;
    const int col0 = blockIdx.x << 6;
    const int wr = (wave >> 1) << 6;   // 0 / 64
    const int wc = (wave & 1) << 5;    // 0 / 32

    const int srA = wave * 32 + (lane >> 2);   // A rows: 2 instrs/wave
    const int srB = wave * 16 + (lane >> 2);   // B rows: 1 instr/wave
    const int skp = (lane & 3) << 3;
    const u16* Ag = A  + (size_t)(row0 + srA) * lda + skp;
    const u16* Bg = WT + (size_t)(col0 + srB) * 1024 + skp;
    u16* Asd0 = &As[(wave * 32) * 32];
    u16* Asd1 = &As[(wave * 32 + 16) * 32];
    u16* Bsd  = &Bs[(wave * 16) * 32];

    f32x4 acc[4][2] = {};

    for (int k0 = 0; k0 < 1024; k0 += 32) {
        __syncthreads();
        __builtin_amdgcn_global_load_lds(
            (const __attribute__((address_space(1))) void*)(Ag + k0),
            (__attribute__((address_space(3))) void*)Asd0, 16, 0, 0);
        __builtin_amdgcn_global_load_lds(
            (const __attribute__((address_space(1))) void*)(Ag + (size_t)16 * lda + k0),
            (__attribute__((address_space(3))) void*)Asd1, 16, 0, 0);
        __builtin_amdgcn_global_load_lds(
            (const __attribute__((address_space(1))) void*)(Bg + k0),
            (__attribute__((address_space(3))) void*)Bsd, 16, 0, 0);
        __syncthreads();
        short8 af[4], bf[2];
#pragma unroll
        for (int i = 0; i < 4; ++i)
            af[i] = *(const short8*)&As[(wr + i * 16 + lm) * 32 + quad * 8];
#pragma unroll
        for (int j = 0; j < 2; ++j)
            bf[j] = *(const short8*)&Bs[(wc + j * 16 + lm) * 32 + quad * 8];
#pragma unroll
        for (int i = 0; i < 4; ++i)
#pragma unroll
            for (int j = 0; j < 2; ++j)
                acc[i][j] = __builtin_amdgcn_mfma_f32_16x16x32_bf16(af[i], bf[j], acc[i][j], 0, 0, 0);
    }
    const int sel = col0 >> 10;
    const float* bias = (sel == 0) ? bs0 : (sel == 1) ? bs1 : (sel == 2) ? bs2 : bs3;
    const int act = (actmask >> sel) & 1;
#pragma unroll
    for (int j = 0; j < 2; ++j) {
        const int colg = col0 + wc + j * 16 + lm;
        const float bj = bias[colg & 1023];
#pragma unroll
        for (int i = 0; i < 4; ++i) {
#pragma unroll
            for (int r = 0; r < 4; ++r) {
                const int rowg = row0 + wr + i * 16 + quad * 4 + r;
                const size_t idx = (size_t)rowg * ldo + colg;
                float v = acc[i][j][r] + bj;
                if (act) v = silu_f(v);
                if (res) v += res[idx];
                if (outf) outf[idx] = v;
                else      outb[idx] = f2bf(v);
            }
        }
    }
}

// ---------------- MFMA SiLU attention on QKVU views (ld=4096) ----------------
// Block = (b, h, 64 s-rows); grid (32,16,2)=1024. 4 waves x 16 s-rows.
// S^T = K @ Q^T -> t-consecutive C regs -> ushort4 P writes. Double-buffered
// P/V^T LDS, ONE barrier per t-iter. Q/K frags direct from global; K pipelined.
// out aliases the q-slot (all q reads precede the loop; block regions disjoint).
__global__ __launch_bounds__(256) void attn_mfma(
    const u16* __restrict__ qkvu, const float* __restrict__ pb, u16* __restrict__ out)
{
    __shared__ u16 Vt[2][64 * 72];
    __shared__ u16 Pl[2][64 * 72];
    __shared__ float pbl[S_];
    const int tid  = threadIdx.x;
    const int wave = tid >> 6;
    const int lane = tid & 63;
    const int lm   = lane & 15;
    const int quad = lane >> 4;
    const int s0 = blockIdx.x << 6;
    const int h  = blockIdx.y;
    const int b  = blockIdx.z;
    const size_t base = (size_t)b * S_ * LQ + (size_t)h * DH;
    const u16* q = qkvu + base;
    const u16* k = qkvu + base + 1024;
    const u16* v = qkvu + base + 2048;
    const int sw = wave << 4;          // wave s-offset (0/16/32/48)

    for (int i = tid; i < S_; i += 256) pbl[i] = pb[(size_t)i * NH + h];

    // Q fragments (B-operand: n=s, k=dh), persist whole kernel
    short8 qf[2];
#pragma unroll
    for (int kk = 0; kk < 2; ++kk)
        qf[kk] = *(const short8*)&q[(size_t)(s0 + sw + lm) * LQ + kk * 32 + quad * 8];

    // K fragments for t0=0 (A-operand: m=t, k=dh)
    short8 kf[4][2];
#pragma unroll
    for (int mt = 0; mt < 4; ++mt)
#pragma unroll
        for (int kk = 0; kk < 2; ++kk)
            kf[mt][kk] = *(const short8*)&k[(size_t)(mt * 16 + lm) * LQ + kk * 32 + quad * 8];

    const int tp  = tid & 31;          // t-pair index for V staging
    const int d0v = (tid >> 5) << 3;   // dh group

    f32x4 accO[4] = {};
    __syncthreads();   // pbl visible

    for (int t0 = 0; t0 < S_; t0 += 64) {
        const int ib = (t0 >> 6) & 1;
        // V loads for this tile
        ushort4 v0a = *(const ushort4*)&v[(size_t)(t0 + 2 * tp) * LQ + d0v];
        ushort4 v0b = *(const ushort4*)&v[(size_t)(t0 + 2 * tp) * LQ + d0v + 4];
        ushort4 v1a = *(const ushort4*)&v[(size_t)(t0 + 2 * tp + 1) * LQ + d0v];
        ushort4 v1b = *(const ushort4*)&v[(size_t)(t0 + 2 * tp + 1) * LQ + d0v + 4];
        // S^T = K @ Q^T (regs only)
        f32x4 st[4] = {};
#pragma unroll
        for (int mt = 0; mt < 4; ++mt)
#pragma unroll
            for (int kk = 0; kk < 2; ++kk)
                st[mt] = __builtin_amdgcn_mfma_f32_16x16x32_bf16(kf[mt][kk], qf[kk], st[mt], 0, 0, 0);
        // stage V^T (pack t-pairs per dh)
        {
            const u16 va[8] = {v0a.x, v0a.y, v0a.z, v0a.w, v0b.x, v0b.y, v0b.z, v0b.w};
            const u16 vb[8] = {v1a.x, v1a.y, v1a.z, v1a.w, v1b.x, v1b.y, v1b.z, v1b.w};
#pragma unroll
            for (int i = 0; i < 8; ++i) {
                uint32_t pk = (uint32_t)va[i] | ((uint32_t)vb[i] << 16);
                *(uint32_t*)&Vt[ib][(d0v + i) * 72 + 2 * tp] = pk;
            }
        }
        // P = silu(0.125*S + pb) -> Pl[ib][s][t]
#pragma unroll
        for (int mt = 0; mt < 4; ++mt) {
            const int tl = mt * 16 + quad * 4;
            float4 pbv = *(const float4*)&pbl[t0 + tl];
            const float pbr[4] = {pbv.x, pbv.y, pbv.z, pbv.w};
            ushort4 pk;
            pk.x = f2bf(silu_f(fmaf(st[mt][0], 0.125f, pbr[0])));
            pk.y = f2bf(silu_f(fmaf(st[mt][1], 0.125f, pbr[1])));
            pk.z = f2bf(silu_f(fmaf(st[mt][2], 0.125f, pbr[2])));
            pk.w = f2bf(silu_f(fmaf(st[mt][3], 0.125f, pbr[3])));
            *(ushort4*)&Pl[ib][(sw + lm) * 72 + tl] = pk;
        }
        __syncthreads();   // buf[ib] visible; prev buf's readers already past
        // prefetch next K tile (overlaps PV)
        if (t0 + 64 < S_) {
#pragma unroll
            for (int mt = 0; mt < 4; ++mt)
#pragma unroll
                for (int kk = 0; kk < 2; ++kk)
                    kf[mt][kk] = *(const short8*)&k[(size_t)(t0 + 64 + mt * 16 + lm) * LQ + kk * 32 + quad * 8];
        }
        // O += P @ V (m=s, n=dh, k=t)
        short8 pf[2], vf[4][2];
#pragma unroll
        for (int kk = 0; kk < 2; ++kk)
            pf[kk] = *(const short8*)&Pl[ib][(sw + lm) * 72 + kk * 32 + quad * 8];
#pragma unroll
        for (int nj = 0; nj < 4; ++nj)
#pragma unroll
            for (int kk = 0; kk < 2; ++kk)
                vf[nj][kk] = *(const short8*)&Vt[ib][(nj * 16 + lm) * 72 + kk * 32 + quad * 8];
#pragma unroll
        for (int nj = 0; nj < 4; ++nj)
#pragma unroll
            for (int kk = 0; kk < 2; ++kk)
                accO[nj] = __builtin_amdgcn_mfma_f32_16x16x32_bf16(pf[kk], vf[nj][kk], accO[nj], 0, 0, 0);
    }
    // store O: col=dh=nj*16+lm, row=s=quad*4+r
#pragma unroll
    for (int nj = 0; nj < 4; ++nj)
#pragma unroll
        for (int r = 0; r < 4; ++r) {
            const int s = s0 + sw + quad * 4 + r;
            out[base + (size_t)s * LQ + nj * 16 + lm] = f2bf(accO[nj][r]);
        }
}

// ---------------- SwiGLU on QKVU: x1=cols[0,1024), x2=[1024,2048) -> cols[2048,3072) ----
__global__ __launch_bounds__(256) void swiglu_kernel(u16* __restrict__ qkvu)
{
    const size_t e = ((size_t)blockIdx.x * 256 + threadIdx.x) << 2;
    const size_t r = e >> 10;
    const int    c = (int)(e & 1023);
    ushort4 a = *(const ushort4*)&qkvu[r * LQ + c];
    ushort4 b = *(const ushort4*)&qkvu[r * LQ + 1024 + c];
    ushort4 o;
    o.x = f2bf(silu_f(bf2f(a.x)) * bf2f(b.x));
    o.y = f2bf(silu_f(bf2f(a.y)) * bf2f(b.y));
    o.z = f2bf(silu_f(bf2f(a.z)) * bf2f(b.z));
    o.w = f2bf(silu_f(bf2f(a.w)) * bf2f(b.w));
    *(ushort4*)&qkvu[r * LQ + 2048 + c] = o;
}

extern "C" void kernel_launch(void* const* d_in, const int* in_sizes, int n_in,
                              void* d_out, int out_size, void* d_ws, size_t ws_size,
                              hipStream_t stream)
{
    const float* x      = (const float*)d_in[0];
    const float* pb     = (const float*)d_in[2];
    const float* wq     = (const float*)d_in[3];
    const float* bq     = (const float*)d_in[4];
    const float* wk     = (const float*)d_in[5];
    const float* bk     = (const float*)d_in[6];
    const float* wv     = (const float*)d_in[7];
    const float* bv     = (const float*)d_in[8];
    const float* wu     = (const float*)d_in[9];
    const float* bu     = (const float*)d_in[10];
    const float* g_ams  = (const float*)d_in[11];
    const float* w0     = (const float*)d_in[12];
    const float* b0     = (const float*)d_in[13];
    const float* w1     = (const float*)d_in[14];
    const float* b1     = (const float*)d_in[15];
    const float* w2     = (const float*)d_in[16];
    const float* b2     = (const float*)d_in[17];
    const float* g_mffn = (const float*)d_in[18];
    float* OUT = (float*)d_out;

    const size_t MI = 1024 * 1024;
    u16* WS   = (u16*)d_ws;                 // 56 MB total
    u16* wT4  = WS;                         // [4096][1024]: wq,wk,wv,wu stacked (8 MB)
    u16* w0T  = WS + 4 * MI;                // [1024][1024] (2 MB)
    u16* w2T  = WS + 5 * MI;                // (2 MB)
    u16* w1T  = WS + 6 * MI;                // [2048][1024] (4 MB)
    u16* A0   = WS + 8 * MI;                // [4096][1024] bf16 (8 MB)
    u16* QKVU = WS + 12 * MI;               // [4096][4096] bf16 (32 MB)

    dim3 blk(256);
    dim3 gT(16, 16), gT1(32, 16);
    dim3 gF(64, 32);                        // fused N=4096
    dim3 gG(16, 32);                        // N=1024
    dim3 gG2(32, 32);                       // N=2048

    transpose_cast_kernel<<<gT,  blk, 0, stream>>>(wq, wT4,          1024);
    transpose_cast_kernel<<<gT,  blk, 0, stream>>>(wk, wT4 + 1 * MI, 1024);
    transpose_cast_kernel<<<gT,  blk, 0, stream>>>(wv, wT4 + 2 * MI, 1024);
    transpose_cast_kernel<<<gT,  blk, 0, stream>>>(wu, wT4 + 3 * MI, 1024);
    transpose_cast_kernel<<<gT,  blk, 0, stream>>>(w0, w0T, 1024);
    transpose_cast_kernel<<<gT,  blk, 0, stream>>>(w2, w2T, 1024);
    transpose_cast_kernel<<<gT1, blk, 0, stream>>>(w1, w1T, 2048);

    // 1. xn = rmsnorm(x)*g_ams -> A0
    rmsnorm_kernel<<<ROWS, blk, 0, stream>>>(x, nullptr, D, g_ams, nullptr, 0, A0, D);
    // 2. fused QKVU = xn @ [wq|wk|wv|wu] (+bias, silu on u) -> QKVU
    gemm_mfma<<<gF, blk, 0, stream>>>(A0, D, wT4, bq, bk, bv, bu,
                                      nullptr, QKVU, nullptr, LQ, 0b1000);
    // 3. attention over QKVU views -> q-slot (in-place)
    attn_mfma<<<dim3(S_ / 64, NH, B_), blk, 0, stream>>>(QKVU, pb, QKVU);
    // 4. ams = rmsnorm(attn)*g_ams*u -> A0 (xn dead)
    rmsnorm_kernel<<<ROWS, blk, 0, stream>>>(nullptr, QKVU, LQ, g_ams, QKVU + 3072, LQ, A0, D);
    // 5. o = ams@w0 + b0 + x -> OUT fp32
    gemm_mfma<<<gG, blk, 0, stream>>>(A0, D, w0T, b0, b0, b0, b0,
                                      x, nullptr, OUT, D, 0);
    // 6. o_norm = rmsnorm(o)*g_mffn -> A0 (ams dead)
    rmsnorm_kernel<<<ROWS, blk, 0, stream>>>(OUT, nullptr, D, g_mffn, nullptr, 0, A0, D);
    // 7. x12 = o_norm@w1 + b1 -> QKVU cols[0,2048) (q,k slots dead)
    gemm_mfma<<<gG2, blk, 0, stream>>>(A0, D, w1T, b1, b1 + 1024, b1, b1,
                                       nullptr, QKVU, nullptr, LQ, 0);
    // 8. swiglu -> QKVU cols[2048,3072) (v slot dead)
    swiglu_kernel<<<ROWS * D / 1024, blk, 0, stream>>>(QKVU);
    // 9. out = swiglu@w2 + b2 + o -> OUT (in-place residual)
    gemm_mfma<<<gG, blk, 0, stream>>>(QKVU + 2048, LQ, w2T, b2, b2, b2, b2,
                                      OUT, nullptr, OUT, D, 0);
    (void)ws_size; (void)in_sizes; (void)n_in; (void)out_size;
}

// Round 7
// 406.892 us; speedup vs baseline: 1.2330x; 1.2330x over previous
//
#include <hip/hip_runtime.h>
#include <stdint.h>
#include <math.h>

// FuXi block on MI355X, round 7: attention latency round.
// - attn: 128 s-row blocks (512 = 2/CU), K+V register-pipelined one t-tile ahead,
//   double-buffered P/V^T LDS, ONE barrier per t-iter. Theory: round-5/6 attn was
//   global-load-latency-bound (10.4k cyc/iter vs ~700 of work).
// - all 7 weight transposes fused into one dispatch.
// - GEMMs/rmsnorm/swiglu unchanged from round 6.

#define D    1024
#define NH   16
#define DH   64
#define B_   2
#define S_   2048
#define ROWS 4096
#define LQ   4096          // QKVU row stride
#define EPSR 1e-8f

typedef unsigned short u16;
typedef __attribute__((ext_vector_type(8))) short short8;
typedef __attribute__((ext_vector_type(4))) float f32x4;

__device__ __forceinline__ float bf2f(u16 u) {
    union { uint32_t i; float f; } c; c.i = ((uint32_t)u) << 16; return c.f;
}
__device__ __forceinline__ u16 f2bf(float f) {
    union { float f; uint32_t i; } c; c.f = f;
    uint32_t x = c.i;
    x += 0x7fffu + ((x >> 16) & 1u);
    return (u16)(x >> 16);
}
__device__ __forceinline__ float silu_f(float v) { return v / (1.0f + __expf(-v)); }

// ---------------- fused weight prep: 7 transposes in one dispatch ----------------
// z: 0..3 -> wq/wk/wv/wu into wT4 quarter z; 4 -> w0; 5 -> w2; 6,7 -> w1 halves.
__global__ __launch_bounds__(256) void transpose_all_kernel(
    const float* __restrict__ wq, const float* __restrict__ wk,
    const float* __restrict__ wv, const float* __restrict__ wu,
    const float* __restrict__ w0, const float* __restrict__ w2,
    const float* __restrict__ w1,
    u16* __restrict__ wT4, u16* __restrict__ w0T,
    u16* __restrict__ w2T, u16* __restrict__ w1T)
{
    const unsigned MI = 1u << 20;
    const int z = blockIdx.z;
    const float* W; u16* WT; int N; int noff = 0;
    switch (z) {
        case 0: W = wq; WT = wT4;          N = 1024; break;
        case 1: W = wk; WT = wT4 + 1 * MI; N = 1024; break;
        case 2: W = wv; WT = wT4 + 2 * MI; N = 1024; break;
        case 3: W = wu; WT = wT4 + 3 * MI; N = 1024; break;
        case 4: W = w0; WT = w0T;          N = 1024; break;
        case 5: W = w2; WT = w2T;          N = 1024; break;
        case 6: W = w1; WT = w1T;          N = 2048; noff = 0;    break;
        default:W = w1; WT = w1T;          N = 2048; noff = 1024; break;
    }
    __shared__ float T[64][65];
    const int tid = threadIdx.x;
    const int n0 = (blockIdx.x << 6) + noff;   // global col in W / row in WT
    const int k0 = blockIdx.y << 6;
    const int rr = tid >> 4;
    const int cc = (tid & 15) << 2;
#pragma unroll
    for (int l = 0; l < 4; ++l) {
        const int r = rr + (l << 4);
        float4 v = *(const float4*)&W[(size_t)(k0 + r) * N + n0 + cc];
        T[cc + 0][r] = v.x; T[cc + 1][r] = v.y;
        T[cc + 2][r] = v.z; T[cc + 3][r] = v.w;
    }
    __syncthreads();
    const int n  = tid >> 2;
    const int ks = (tid & 3) << 4;
#pragma unroll
    for (int m = 0; m < 4; ++m) {
        const int k = ks + (m << 2);
        float4 v = *(const float4*)&T[n][k];
        ushort4 o;
        o.x = f2bf(v.x); o.y = f2bf(v.y); o.z = f2bf(v.z); o.w = f2bf(v.w);
        *(ushort4*)&WT[(size_t)(n0 + n) * 1024 + k0 + k] = o;
    }
}

// ---------------- RMSNorm: strided in (fp32 or bf16), strided bf16 mul, bf16 out ----
__global__ __launch_bounds__(256) void rmsnorm_kernel(
    const float* __restrict__ inf, const u16* __restrict__ inb, int ldi,
    const float* __restrict__ g,
    const u16* __restrict__ mul, int ldm,
    u16* __restrict__ out, int ldo)
{
    const int row = blockIdx.x;
    const int tid = threadIdx.x;
    const int c = tid << 2;
    float x0, x1, x2, x3;
    if (inb) {
        ushort4 xi = *(const ushort4*)&inb[(size_t)row * ldi + c];
        x0 = bf2f(xi.x); x1 = bf2f(xi.y); x2 = bf2f(xi.z); x3 = bf2f(xi.w);
    } else {
        float4 xi = *(const float4*)&inf[(size_t)row * ldi + c];
        x0 = xi.x; x1 = xi.y; x2 = xi.z; x3 = xi.w;
    }
    float ss = x0*x0 + x1*x1 + x2*x2 + x3*x3;
#pragma unroll
    for (int off = 32; off > 0; off >>= 1) ss += __shfl_down(ss, off, 64);
    __shared__ float red[4];
    if ((tid & 63) == 0) red[tid >> 6] = ss;
    __syncthreads();
    float r = rsqrtf((red[0] + red[1] + red[2] + red[3]) * (1.0f / D) + EPSR);
    float4 gv = *(const float4*)&g[c];
    float v0 = x0 * r * gv.x, v1 = x1 * r * gv.y, v2 = x2 * r * gv.z, v3 = x3 * r * gv.w;
    if (mul) {
        ushort4 mi = *(const ushort4*)&mul[(size_t)row * ldm + c];
        v0 *= bf2f(mi.x); v1 *= bf2f(mi.y); v2 *= bf2f(mi.z); v3 *= bf2f(mi.w);
    }
    ushort4 o;
    o.x = f2bf(v0); o.y = f2bf(v1); o.z = f2bf(v2); o.w = f2bf(v3);
    *(ushort4*)&out[(size_t)row * ldo + c] = o;
}

// ---------------- MFMA GEMM: C[4096,N] = A[4096,1024](bf16,lda) @ WT^T ----------------
// Tile 128x64, 4 waves as 2x2 (each 64x32), BK=32, global_load_lds w=16.
// Bias/act per 1024-col chunk (sel = col0>>10, block-uniform). res may alias outf.
__global__ __launch_bounds__(256) void gemm_mfma(
    const u16* __restrict__ A, int lda, const u16* __restrict__ WT,
    const float* __restrict__ bs0, const float* __restrict__ bs1,
    const float* __restrict__ bs2, const float* __restrict__ bs3,
    const float* __restrict__ res,
    u16* __restrict__ outb, float* __restrict__ outf,
    int ldo, int actmask)
{
    __shared__ u16 As[128 * 32];
    __shared__ u16 Bs[64 * 32];
    const int tid  = threadIdx.x;
    const int wave = tid >> 6;
    const int lane = tid & 63;
    const int lm   = lane & 15;
    const int quad = lane >> 4;
    const int row0 = blockIdx.y << 7;
    const int col0 = blockIdx.x << 6;
    const int wr = (wave >> 1) << 6;
    const int wc = (wave & 1) << 5;

    const int srA = wave * 32 + (lane >> 2);
    const int srB = wave * 16 + (lane >> 2);
    const int skp = (lane & 3) << 3;
    const u16* Ag = A  + (size_t)(row0 + srA) * lda + skp;
    const u16* Bg = WT + (size_t)(col0 + srB) * 1024 + skp;
    u16* Asd0 = &As[(wave * 32) * 32];
    u16* Asd1 = &As[(wave * 32 + 16) * 32];
    u16* Bsd  = &Bs[(wave * 16) * 32];

    f32x4 acc[4][2] = {};

    for (int k0 = 0; k0 < 1024; k0 += 32) {
        __syncthreads();
        __builtin_amdgcn_global_load_lds(
            (const __attribute__((address_space(1))) void*)(Ag + k0),
            (__attribute__((address_space(3))) void*)Asd0, 16, 0, 0);
        __builtin_amdgcn_global_load_lds(
            (const __attribute__((address_space(1))) void*)(Ag + (size_t)16 * lda + k0),
            (__attribute__((address_space(3))) void*)Asd1, 16, 0, 0);
        __builtin_amdgcn_global_load_lds(
            (const __attribute__((address_space(1))) void*)(Bg + k0),
            (__attribute__((address_space(3))) void*)Bsd, 16, 0, 0);
        __syncthreads();
        short8 af[4], bf[2];
#pragma unroll
        for (int i = 0; i < 4; ++i)
            af[i] = *(const short8*)&As[(wr + i * 16 + lm) * 32 + quad * 8];
#pragma unroll
        for (int j = 0; j < 2; ++j)
            bf[j] = *(const short8*)&Bs[(wc + j * 16 + lm) * 32 + quad * 8];
#pragma unroll
        for (int i = 0; i < 4; ++i)
#pragma unroll
            for (int j = 0; j < 2; ++j)
                acc[i][j] = __builtin_amdgcn_mfma_f32_16x16x32_bf16(af[i], bf[j], acc[i][j], 0, 0, 0);
    }
    const int sel = col0 >> 10;
    const float* bias = (sel == 0) ? bs0 : (sel == 1) ? bs1 : (sel == 2) ? bs2 : bs3;
    const int act = (actmask >> sel) & 1;
#pragma unroll
    for (int j = 0; j < 2; ++j) {
        const int colg = col0 + wc + j * 16 + lm;
        const float bj = bias[colg & 1023];
#pragma unroll
        for (int i = 0; i < 4; ++i) {
#pragma unroll
            for (int r = 0; r < 4; ++r) {
                const int rowg = row0 + wr + i * 16 + quad * 4 + r;
                const size_t idx = (size_t)rowg * ldo + colg;
                float v = acc[i][j][r] + bj;
                if (act) v = silu_f(v);
                if (res) v += res[idx];
                if (outf) outf[idx] = v;
                else      outb[idx] = f2bf(v);
            }
        }
    }
}

// ---------------- MFMA SiLU attention, register-pipelined ----------------
// Block = (b, h, 128 s-rows); grid (16,16,2)=512 = 2/CU. 4 waves x 32 s-rows.
// K frags + V regs prefetched ONE t-tile ahead (hides ~900cyc global latency).
// S^T = K@Q^T -> t-consecutive C regs -> ushort4 P writes. Double-buffered
// P/V^T LDS, ONE barrier per iter (cross-iter WAR separated by that barrier).
// out aliases q-slot: all q reads precede loop; writes only cols[h*64..] rows[s0..].
__global__ __launch_bounds__(256, 2) void attn_mfma(
    const u16* __restrict__ qkvu, const float* __restrict__ pb, u16* __restrict__ out)
{
    __shared__ u16 Vt[2][64 * 72];
    __shared__ u16 Pl[2][128 * 72];
    __shared__ float pbl[S_];
    const int tid  = threadIdx.x;
    const int wave = tid >> 6;
    const int lane = tid & 63;
    const int lm   = lane & 15;
    const int quad = lane >> 4;
    const int s0 = blockIdx.x << 7;
    const int h  = blockIdx.y;
    const int b  = blockIdx.z;
    const size_t base = (size_t)b * S_ * LQ + (size_t)h * DH;
    const u16* q = qkvu + base;
    const u16* k = qkvu + base + 1024;
    const u16* v = qkvu + base + 2048;
    const int sw = wave << 5;          // 0/32/64/96

    for (int i = tid; i < S_; i += 256) pbl[i] = pb[(size_t)i * NH + h];

    // Q fragments (B-operand: n=s, k=dh), persist whole kernel
    short8 qf[2][2];
#pragma unroll
    for (int ns = 0; ns < 2; ++ns)
#pragma unroll
        for (int kk = 0; kk < 2; ++kk)
            qf[ns][kk] = *(const short8*)&q[(size_t)(s0 + sw + ns * 16 + lm) * LQ + kk * 32 + quad * 8];

    // current K frags (A-operand: m=t, k=dh) and V regs for t0=0
    short8 kf[4][2];
#pragma unroll
    for (int mt = 0; mt < 4; ++mt)
#pragma unroll
        for (int kk = 0; kk < 2; ++kk)
            kf[mt][kk] = *(const short8*)&k[(size_t)(mt * 16 + lm) * LQ + kk * 32 + quad * 8];
    const int tp  = tid & 31;          // t-pair for V staging (block-wide map)
    const int d0v = (tid >> 5) << 3;   // dh group
    ushort4 vc[4];
    vc[0] = *(const ushort4*)&v[(size_t)(2 * tp) * LQ + d0v];
    vc[1] = *(const ushort4*)&v[(size_t)(2 * tp) * LQ + d0v + 4];
    vc[2] = *(const ushort4*)&v[(size_t)(2 * tp + 1) * LQ + d0v];
    vc[3] = *(const ushort4*)&v[(size_t)(2 * tp + 1) * LQ + d0v + 4];

    f32x4 accO[2][4] = {};
    __syncthreads();   // pbl visible

#pragma unroll 2
    for (int t0 = 0; t0 < S_; t0 += 64) {
        const int ib = (t0 >> 6) & 1;
        const int tn = (t0 + 64 < S_) ? t0 + 64 : t0;   // clamp (last-iter prefetch harmless)
        // ---- prefetch next tile's K frags + V regs (no waits on these here) ----
        short8 kn[4][2];
#pragma unroll
        for (int mt = 0; mt < 4; ++mt)
#pragma unroll
            for (int kk = 0; kk < 2; ++kk)
                kn[mt][kk] = *(const short8*)&k[(size_t)(tn + mt * 16 + lm) * LQ + kk * 32 + quad * 8];
        ushort4 vn[4];
        vn[0] = *(const ushort4*)&v[(size_t)(tn + 2 * tp) * LQ + d0v];
        vn[1] = *(const ushort4*)&v[(size_t)(tn + 2 * tp) * LQ + d0v + 4];
        vn[2] = *(const ushort4*)&v[(size_t)(tn + 2 * tp + 1) * LQ + d0v];
        vn[3] = *(const ushort4*)&v[(size_t)(tn + 2 * tp + 1) * LQ + d0v + 4];
        // ---- S^T = K @ Q^T on current regs ----
        f32x4 st[4][2] = {};
#pragma unroll
        for (int mt = 0; mt < 4; ++mt)
#pragma unroll
            for (int ns = 0; ns < 2; ++ns)
#pragma unroll
                for (int kk = 0; kk < 2; ++kk)
                    st[mt][ns] = __builtin_amdgcn_mfma_f32_16x16x32_bf16(kf[mt][kk], qf[ns][kk], st[mt][ns], 0, 0, 0);
        // ---- stage V^T from current V regs (pack t-pairs per dh) ----
        {
            const u16 va[8] = {vc[0].x, vc[0].y, vc[0].z, vc[0].w, vc[1].x, vc[1].y, vc[1].z, vc[1].w};
            const u16 vb[8] = {vc[2].x, vc[2].y, vc[2].z, vc[2].w, vc[3].x, vc[3].y, vc[3].z, vc[3].w};
#pragma unroll
            for (int i = 0; i < 8; ++i) {
                uint32_t pk = (uint32_t)va[i] | ((uint32_t)vb[i] << 16);
                *(uint32_t*)&Vt[ib][(d0v + i) * 72 + 2 * tp] = pk;
            }
        }
        // ---- P = silu(0.125*S + pb) -> Pl[ib][s][t] ----
#pragma unroll
        for (int mt = 0; mt < 4; ++mt) {
            const int tl = mt * 16 + quad * 4;
            float4 pbv = *(const float4*)&pbl[t0 + tl];
            const float pbr[4] = {pbv.x, pbv.y, pbv.z, pbv.w};
#pragma unroll
            for (int ns = 0; ns < 2; ++ns) {
                ushort4 pk;
                pk.x = f2bf(silu_f(fmaf(st[mt][ns][0], 0.125f, pbr[0])));
                pk.y = f2bf(silu_f(fmaf(st[mt][ns][1], 0.125f, pbr[1])));
                pk.z = f2bf(silu_f(fmaf(st[mt][ns][2], 0.125f, pbr[2])));
                pk.w = f2bf(silu_f(fmaf(st[mt][ns][3], 0.125f, pbr[3])));
                *(ushort4*)&Pl[ib][(sw + ns * 16 + lm) * 72 + tl] = pk;
            }
        }
        __syncthreads();   // buf[ib] visible; prev-buf WAR separated by this barrier
        // ---- O += P @ V (m=s, n=dh, k=t) ----
        short8 pf[2][2], vf[4][2];
#pragma unroll
        for (int mi = 0; mi < 2; ++mi)
#pragma unroll
            for (int kk = 0; kk < 2; ++kk)
                pf[mi][kk] = *(const short8*)&Pl[ib][(sw + mi * 16 + lm) * 72 + kk * 32 + quad * 8];
#pragma unroll
        for (int nj = 0; nj < 4; ++nj)
#pragma unroll
            for (int kk = 0; kk < 2; ++kk)
                vf[nj][kk] = *(const short8*)&Vt[ib][(nj * 16 + lm) * 72 + kk * 32 + quad * 8];
#pragma unroll
        for (int mi = 0; mi < 2; ++mi)
#pragma unroll
            for (int nj = 0; nj < 4; ++nj)
#pragma unroll
                for (int kk = 0; kk < 2; ++kk)
                    accO[mi][nj] = __builtin_amdgcn_mfma_f32_16x16x32_bf16(pf[mi][kk], vf[nj][kk], accO[mi][nj], 0, 0, 0);
        // ---- rotate pipelined regs ----
#pragma unroll
        for (int mt = 0; mt < 4; ++mt)
#pragma unroll
            for (int kk = 0; kk < 2; ++kk)
                kf[mt][kk] = kn[mt][kk];
#pragma unroll
        for (int i = 0; i < 4; ++i) vc[i] = vn[i];
    }
    // store O: col=dh=nj*16+lm, row=s
#pragma unroll
    for (int mi = 0; mi < 2; ++mi)
#pragma unroll
        for (int nj = 0; nj < 4; ++nj)
#pragma unroll
            for (int r = 0; r < 4; ++r) {
                const int s = s0 + sw + mi * 16 + quad * 4 + r;
                out[base + (size_t)s * LQ + nj * 16 + lm] = f2bf(accO[mi][nj][r]);
            }
}

// ---------------- SwiGLU on QKVU: x1=cols[0,1024), x2=[1024,2048) -> [2048,3072) ----
__global__ __launch_bounds__(256) void swiglu_kernel(u16* __restrict__ qkvu)
{
    const size_t e = ((size_t)blockIdx.x * 256 + threadIdx.x) << 2;
    const size_t r = e >> 10;
    const int    c = (int)(e & 1023);
    ushort4 a = *(const ushort4*)&qkvu[r * LQ + c];
    ushort4 b = *(const ushort4*)&qkvu[r * LQ + 1024 + c];
    ushort4 o;
    o.x = f2bf(silu_f(bf2f(a.x)) * bf2f(b.x));
    o.y = f2bf(silu_f(bf2f(a.y)) * bf2f(b.y));
    o.z = f2bf(silu_f(bf2f(a.z)) * bf2f(b.z));
    o.w = f2bf(silu_f(bf2f(a.w)) * bf2f(b.w));
    *(ushort4*)&qkvu[r * LQ + 2048 + c] = o;
}

extern "C" void kernel_launch(void* const* d_in, const int* in_sizes, int n_in,
                              void* d_out, int out_size, void* d_ws, size_t ws_size,
                              hipStream_t stream)
{
    const float* x      = (const float*)d_in[0];
    const float* pb     = (const float*)d_in[2];
    const float* wq     = (const float*)d_in[3];
    const float* bq     = (const float*)d_in[4];
    const float* wk     = (const float*)d_in[5];
    const float* bk     = (const float*)d_in[6];
    const float* wv     = (const float*)d_in[7];
    const float* bv     = (const float*)d_in[8];
    const float* wu     = (const float*)d_in[9];
    const float* bu     = (const float*)d_in[10];
    const float* g_ams  = (const float*)d_in[11];
    const float* w0     = (const float*)d_in[12];
    const float* b0     = (const float*)d_in[13];
    const float* w1     = (const float*)d_in[14];
    const float* b1     = (const float*)d_in[15];
    const float* w2     = (const float*)d_in[16];
    const float* b2     = (const float*)d_in[17];
    const float* g_mffn = (const float*)d_in[18];
    float* OUT = (float*)d_out;

    const size_t MI = 1024 * 1024;
    u16* WS   = (u16*)d_ws;                 // 56 MB total
    u16* wT4  = WS;                         // [4096][1024] stacked wq|wk|wv|wu
    u16* w0T  = WS + 4 * MI;
    u16* w2T  = WS + 5 * MI;
    u16* w1T  = WS + 6 * MI;                // [2048][1024]
    u16* A0   = WS + 8 * MI;                // [4096][1024] bf16
    u16* QKVU = WS + 12 * MI;               // [4096][4096] bf16

    dim3 blk(256);
    dim3 gF(64, 32);                        // fused N=4096
    dim3 gG(16, 32);                        // N=1024
    dim3 gG2(32, 32);                       // N=2048

    // 0. all weight transposes, one dispatch
    transpose_all_kernel<<<dim3(16, 16, 8), blk, 0, stream>>>(
        wq, wk, wv, wu, w0, w2, w1, wT4, w0T, w2T, w1T);

    // 1. xn = rmsnorm(x)*g_ams -> A0
    rmsnorm_kernel<<<ROWS, blk, 0, stream>>>(x, nullptr, D, g_ams, nullptr, 0, A0, D);
    // 2. fused QKVU = xn @ [wq|wk|wv|wu] (+bias, silu on u) -> QKVU
    gemm_mfma<<<gF, blk, 0, stream>>>(A0, D, wT4, bq, bk, bv, bu,
                                      nullptr, QKVU, nullptr, LQ, 0b1000);
    // 3. attention over QKVU views -> q-slot (in-place)
    attn_mfma<<<dim3(S_ / 128, NH, B_), blk, 0, stream>>>(QKVU, pb, QKVU);
    // 4. ams = rmsnorm(attn)*g_ams*u -> A0 (xn dead)
    rmsnorm_kernel<<<ROWS, blk, 0, stream>>>(nullptr, QKVU, LQ, g_ams, QKVU + 3072, LQ, A0, D);
    // 5. o = ams@w0 + b0 + x -> OUT fp32
    gemm_mfma<<<gG, blk, 0, stream>>>(A0, D, w0T, b0, b0, b0, b0,
                                      x, nullptr, OUT, D, 0);
    // 6. o_norm = rmsnorm(o)*g_mffn -> A0 (ams dead)
    rmsnorm_kernel<<<ROWS, blk, 0, stream>>>(OUT, nullptr, D, g_mffn, nullptr, 0, A0, D);
    // 7. x12 = o_norm@w1 + b1 -> QKVU cols[0,2048) (q,k slots dead)
    gemm_mfma<<<gG2, blk, 0, stream>>>(A0, D, w1T, b1, b1 + 1024, b1, b1,
                                       nullptr, QKVU, nullptr, LQ, 0);
    // 8. swiglu -> QKVU cols[2048,3072) (v slot dead)
    swiglu_kernel<<<ROWS * D / 1024, blk, 0, stream>>>(QKVU);
    // 9. out = swiglu@w2 + b2 + o -> OUT (in-place residual)
    gemm_mfma<<<gG, blk, 0, stream>>>(QKVU + 2048, LQ, w2T, b2, b2, b2, b2,
                                      OUT, nullptr, OUT, D, 0);
    (void)ws_size; (void)in_sizes; (void)n_in; (void)out_size;
}

// Round 8
// 383.134 us; speedup vs baseline: 1.3094x; 1.0620x over previous
//
#include <hip/hip_runtime.h>
#include <stdint.h>
#include <math.h>

// FuXi block on MI355X, round 8: attention VMEM-transaction round.
// - V pre-transposed to VT[b][h][dh][t] in QKVU GEMM epilogue (VT lives in d_out,
//   dead after attn, overwritten by o in step 5).
// - attn: K-tile + VT-tile staged block-cooperatively via global_load_lds
//   (8 lines/instr, zero redundancy; XOR chunk swizzle for conflict-free ds_read_b128).
//   P is intra-wave LDS only (no barrier); ONE barrier/iter for tile double-buffer.
// - QKVU & w1 GEMMs: m97 128x128 motif (16 MFMA/wave/iter). w0/w2: 128x64.

#define D    1024
#define NH   16
#define DH   64
#define B_   2
#define S_   2048
#define ROWS 4096
#define LQ   4096          // QKVU row stride
#define EPSR 1e-8f

typedef unsigned short u16;
typedef __attribute__((ext_vector_type(8))) short short8;
typedef __attribute__((ext_vector_type(4))) float f32x4;

__device__ __forceinline__ float bf2f(u16 u) {
    union { uint32_t i; float f; } c; c.i = ((uint32_t)u) << 16; return c.f;
}
__device__ __forceinline__ u16 f2bf(float f) {
    union { float f; uint32_t i; } c; c.f = f;
    uint32_t x = c.i;
    x += 0x7fffu + ((x >> 16) & 1u);
    return (u16)(x >> 16);
}
// pack two f32 -> (bf16(a) | bf16(b)<<16), round-half-up via +0x8000 then v_perm
__device__ __forceinline__ uint32_t pack2bf(float a, float b) {
    union { float f; uint32_t i; } ca, cb; ca.f = a; cb.f = b;
    return __builtin_amdgcn_perm(cb.i + 0x8000u, ca.i + 0x8000u, 0x07060302);
}
__device__ __forceinline__ float silu_f(float v) { return v / (1.0f + __expf(-v)); }

// ---------------- fused weight prep: 7 transposes in one dispatch ----------------
__global__ __launch_bounds__(256) void transpose_all_kernel(
    const float* __restrict__ wq, const float* __restrict__ wk,
    const float* __restrict__ wv, const float* __restrict__ wu,
    const float* __restrict__ w0, const float* __restrict__ w2,
    const float* __restrict__ w1,
    u16* __restrict__ wT4, u16* __restrict__ w0T,
    u16* __restrict__ w2T, u16* __restrict__ w1T)
{
    const unsigned MI = 1u << 20;
    const int z = blockIdx.z;
    const float* W; u16* WT; int N; int noff = 0;
    switch (z) {
        case 0: W = wq; WT = wT4;          N = 1024; break;
        case 1: W = wk; WT = wT4 + 1 * MI; N = 1024; break;
        case 2: W = wv; WT = wT4 + 2 * MI; N = 1024; break;
        case 3: W = wu; WT = wT4 + 3 * MI; N = 1024; break;
        case 4: W = w0; WT = w0T;          N = 1024; break;
        case 5: W = w2; WT = w2T;          N = 1024; break;
        case 6: W = w1; WT = w1T;          N = 2048; noff = 0;    break;
        default:W = w1; WT = w1T;          N = 2048; noff = 1024; break;
    }
    __shared__ float T[64][65];
    const int tid = threadIdx.x;
    const int n0 = (blockIdx.x << 6) + noff;
    const int k0 = blockIdx.y << 6;
    const int rr = tid >> 4;
    const int cc = (tid & 15) << 2;
#pragma unroll
    for (int l = 0; l < 4; ++l) {
        const int r = rr + (l << 4);
        float4 v = *(const float4*)&W[(size_t)(k0 + r) * N + n0 + cc];
        T[cc + 0][r] = v.x; T[cc + 1][r] = v.y;
        T[cc + 2][r] = v.z; T[cc + 3][r] = v.w;
    }
    __syncthreads();
    const int n  = tid >> 2;
    const int ks = (tid & 3) << 4;
#pragma unroll
    for (int m = 0; m < 4; ++m) {
        const int k = ks + (m << 2);
        float4 v = *(const float4*)&T[n][k];
        ushort4 o;
        o.x = f2bf(v.x); o.y = f2bf(v.y); o.z = f2bf(v.z); o.w = f2bf(v.w);
        *(ushort4*)&WT[(size_t)(n0 + n) * 1024 + k0 + k] = o;
    }
}

// ---------------- RMSNorm ----------------
__global__ __launch_bounds__(256) void rmsnorm_kernel(
    const float* __restrict__ inf, const u16* __restrict__ inb, int ldi,
    const float* __restrict__ g,
    const u16* __restrict__ mul, int ldm,
    u16* __restrict__ out, int ldo)
{
    const int row = blockIdx.x;
    const int tid = threadIdx.x;
    const int c = tid << 2;
    float x0, x1, x2, x3;
    if (inb) {
        ushort4 xi = *(const ushort4*)&inb[(size_t)row * ldi + c];
        x0 = bf2f(xi.x); x1 = bf2f(xi.y); x2 = bf2f(xi.z); x3 = bf2f(xi.w);
    } else {
        float4 xi = *(const float4*)&inf[(size_t)row * ldi + c];
        x0 = xi.x; x1 = xi.y; x2 = xi.z; x3 = xi.w;
    }
    float ss = x0*x0 + x1*x1 + x2*x2 + x3*x3;
#pragma unroll
    for (int off = 32; off > 0; off >>= 1) ss += __shfl_down(ss, off, 64);
    __shared__ float red[4];
    if ((tid & 63) == 0) red[tid >> 6] = ss;
    __syncthreads();
    float r = rsqrtf((red[0] + red[1] + red[2] + red[3]) * (1.0f / D) + EPSR);
    float4 gv = *(const float4*)&g[c];
    float v0 = x0 * r * gv.x, v1 = x1 * r * gv.y, v2 = x2 * r * gv.z, v3 = x3 * r * gv.w;
    if (mul) {
        ushort4 mi = *(const ushort4*)&mul[(size_t)row * ldm + c];
        v0 *= bf2f(mi.x); v1 *= bf2f(mi.y); v2 *= bf2f(mi.z); v3 *= bf2f(mi.w);
    }
    ushort4 o;
    o.x = f2bf(v0); o.y = f2bf(v1); o.z = f2bf(v2); o.w = f2bf(v3);
    *(ushort4*)&out[(size_t)row * ldo + c] = o;
}

// ---------------- 128x128 MFMA GEMM (m97 motif), bf16 out ----------------
// A is [4096][1024] bf16; WT is [N][1024] bf16. Bias/act per 1024-col chunk.
// If sel==vtsel: write that chunk transposed to VT[b][h][dh][t] (packed ushort4).
__global__ __launch_bounds__(256) void gemm128(
    const u16* __restrict__ A, const u16* __restrict__ WT,
    const float* __restrict__ bs0, const float* __restrict__ bs1,
    const float* __restrict__ bs2, const float* __restrict__ bs3,
    u16* __restrict__ outb, int ldo, int actmask,
    u16* __restrict__ VT, int vtsel)
{
    __shared__ u16 As[128 * 32];
    __shared__ u16 Bs[128 * 32];
    const int tid  = threadIdx.x;
    const int wave = tid >> 6;
    const int lane = tid & 63;
    const int lm   = lane & 15;
    const int quad = lane >> 4;
    const int row0 = blockIdx.y << 7;
    const int col0 = blockIdx.x << 7;
    const int wr = (wave >> 1) << 6;
    const int wc = (wave & 1) << 6;

    const int srow = wave * 32 + (lane >> 2);
    const int skp  = (lane & 3) << 3;
    const u16* Ag = A  + (size_t)(row0 + srow) * 1024 + skp;
    const u16* Bg = WT + (size_t)(col0 + srow) * 1024 + skp;
    u16* Asd0 = &As[(wave * 32) * 32];
    u16* Asd1 = &As[(wave * 32 + 16) * 32];
    u16* Bsd0 = &Bs[(wave * 32) * 32];
    u16* Bsd1 = &Bs[(wave * 32 + 16) * 32];

    f32x4 acc[4][4] = {};

    for (int k0 = 0; k0 < 1024; k0 += 32) {
        __syncthreads();
        __builtin_amdgcn_global_load_lds(
            (const __attribute__((address_space(1))) void*)(Ag + k0),
            (__attribute__((address_space(3))) void*)Asd0, 16, 0, 0);
        __builtin_amdgcn_global_load_lds(
            (const __attribute__((address_space(1))) void*)(Ag + 16 * 1024 + k0),
            (__attribute__((address_space(3))) void*)Asd1, 16, 0, 0);
        __builtin_amdgcn_global_load_lds(
            (const __attribute__((address_space(1))) void*)(Bg + k0),
            (__attribute__((address_space(3))) void*)Bsd0, 16, 0, 0);
        __builtin_amdgcn_global_load_lds(
            (const __attribute__((address_space(1))) void*)(Bg + 16 * 1024 + k0),
            (__attribute__((address_space(3))) void*)Bsd1, 16, 0, 0);
        __syncthreads();
        short8 af[4], bf[4];
#pragma unroll
        for (int i = 0; i < 4; ++i)
            af[i] = *(const short8*)&As[(wr + i * 16 + lm) * 32 + quad * 8];
#pragma unroll
        for (int j = 0; j < 4; ++j)
            bf[j] = *(const short8*)&Bs[(wc + j * 16 + lm) * 32 + quad * 8];
#pragma unroll
        for (int i = 0; i < 4; ++i)
#pragma unroll
            for (int j = 0; j < 4; ++j)
                acc[i][j] = __builtin_amdgcn_mfma_f32_16x16x32_bf16(af[i], bf[j], acc[i][j], 0, 0, 0);
    }
    const int sel = col0 >> 10;
    const float* bias = (sel == 0) ? bs0 : (sel == 1) ? bs1 : (sel == 2) ? bs2 : bs3;
    const int act = (actmask >> sel) & 1;
    if (VT && sel == vtsel) {
        // transposed write: VT[b][h][dh][t], t-consecutive regs -> ushort4 stores
        const int b = row0 >> 11;
#pragma unroll
        for (int j = 0; j < 4; ++j) {
            const int c2 = (col0 + wc + j * 16 + lm) & 1023;
            const int h  = c2 >> 6;
            const int dh = c2 & 63;
            const float bj = bias[c2];
            u16* vrow = VT + ((size_t)(b * NH + h) * 64 + dh) * (size_t)S_;
#pragma unroll
            for (int i = 0; i < 4; ++i) {
                const int tb = (row0 & 2047) + wr + i * 16 + quad * 4;
                ushort4 o;
                o.x = f2bf(acc[i][j][0] + bj);
                o.y = f2bf(acc[i][j][1] + bj);
                o.z = f2bf(acc[i][j][2] + bj);
                o.w = f2bf(acc[i][j][3] + bj);
                *(ushort4*)&vrow[tb] = o;
            }
        }
    } else {
#pragma unroll
        for (int j = 0; j < 4; ++j) {
            const int colg = col0 + wc + j * 16 + lm;
            const float bj = bias[colg & 1023];
#pragma unroll
            for (int i = 0; i < 4; ++i) {
#pragma unroll
                for (int r = 0; r < 4; ++r) {
                    const int rowg = row0 + wr + i * 16 + quad * 4 + r;
                    float v = acc[i][j][r] + bj;
                    if (act) v = silu_f(v);
                    outb[(size_t)rowg * ldo + colg] = f2bf(v);
                }
            }
        }
    }
}

// ---------------- 128x64 MFMA GEMM (for N=1024: w0, w2) ----------------
__global__ __launch_bounds__(256) void gemm64(
    const u16* __restrict__ A, int lda, const u16* __restrict__ WT,
    const float* __restrict__ bias,
    const float* __restrict__ res,
    float* __restrict__ outf, int ldo)
{
    __shared__ u16 As[128 * 32];
    __shared__ u16 Bs[64 * 32];
    const int tid  = threadIdx.x;
    const int wave = tid >> 6;
    const int lane = tid & 63;
    const int lm   = lane & 15;
    const int quad = lane >> 4;
    const int row0 = blockIdx.y << 7;
    const int col0 = blockIdx.x << 6;
    const int wr = (wave >> 1) << 6;
    const int wc = (wave & 1) << 5;

    const int srA = wave * 32 + (lane >> 2);
    const int srB = wave * 16 + (lane >> 2);
    const int skp = (lane & 3) << 3;
    const u16* Ag = A  + (size_t)(row0 + srA) * lda + skp;
    const u16* Bg = WT + (size_t)(col0 + srB) * 1024 + skp;
    u16* Asd0 = &As[(wave * 32) * 32];
    u16* Asd1 = &As[(wave * 32 + 16) * 32];
    u16* Bsd  = &Bs[(wave * 16) * 32];

    f32x4 acc[4][2] = {};

    for (int k0 = 0; k0 < 1024; k0 += 32) {
        __syncthreads();
        __builtin_amdgcn_global_load_lds(
            (const __attribute__((address_space(1))) void*)(Ag + k0),
            (__attribute__((address_space(3))) void*)Asd0, 16, 0, 0);
        __builtin_amdgcn_global_load_lds(
            (const __attribute__((address_space(1))) void*)(Ag + (size_t)16 * lda + k0),
            (__attribute__((address_space(3))) void*)Asd1, 16, 0, 0);
        __builtin_amdgcn_global_load_lds(
            (const __attribute__((address_space(1))) void*)(Bg + k0),
            (__attribute__((address_space(3))) void*)Bsd, 16, 0, 0);
        __syncthreads();
        short8 af[4], bf[2];
#pragma unroll
        for (int i = 0; i < 4; ++i)
            af[i] = *(const short8*)&As[(wr + i * 16 + lm) * 32 + quad * 8];
#pragma unroll
        for (int j = 0; j < 2; ++j)
            bf[j] = *(const short8*)&Bs[(wc + j * 16 + lm) * 32 + quad * 8];
#pragma unroll
        for (int i = 0; i < 4; ++i)
#pragma unroll
            for (int j = 0; j < 2; ++j)
                acc[i][j] = __builtin_amdgcn_mfma_f32_16x16x32_bf16(af[i], bf[j], acc[i][j], 0, 0, 0);
    }
#pragma unroll
    for (int j = 0; j < 2; ++j) {
        const int colg = col0 + wc + j * 16 + lm;
        const float bj = bias[colg];
#pragma unroll
        for (int i = 0; i < 4; ++i) {
#pragma unroll
            for (int r = 0; r < 4; ++r) {
                const int rowg = row0 + wr + i * 16 + quad * 4 + r;
                const size_t idx = (size_t)rowg * ldo + colg;
                float v = acc[i][j][r] + bj;
                if (res) v += res[idx];
                outf[idx] = v;
            }
        }
    }
}

// ---------------- MFMA SiLU attention, glds-staged tiles ----------------
// Block = (b, h, 128 s-rows); 4 waves x 32 s. Per t-iter (64 t):
//  - K-tile [64t][64dh] + VT-tile [64dh][64t] staged via global_load_lds
//    (8 instrs each, 8 cachelines/instr, XOR chunk swizzle c^=row&7)
//  - S^T = K@Q^T; P = silu -> per-wave LDS region (intra-wave, NO barrier)
//  - O += P@V via ds_read_b128 frags; ONE __syncthreads protecting tile dbuf.
__global__ __launch_bounds__(256) void attn_mfma(
    const u16* __restrict__ qkvu, const u16* __restrict__ VT,
    const float* __restrict__ pb, u16* __restrict__ out)
{
    __shared__ u16 Ks[2][64 * 64];
    __shared__ u16 Vs[2][64 * 64];
    __shared__ u16 Pl[128 * 72];
    __shared__ float pbl[S_];
    const int tid  = threadIdx.x;
    const int wave = tid >> 6;
    const int lane = tid & 63;
    const int lm   = lane & 15;
    const int quad = lane >> 4;
    const int s0 = blockIdx.x << 7;
    const int h  = blockIdx.y;
    const int b  = blockIdx.z;
    const size_t base = (size_t)b * S_ * LQ + (size_t)h * DH;
    const u16* q  = qkvu + base;
    const u16* kg = qkvu + base + 1024;
    const u16* vt = VT + (size_t)(b * NH + h) * 64 * S_;
    const int sw = wave << 5;

    for (int i = tid; i < S_; i += 256) pbl[i] = pb[(size_t)i * NH + h];

    // Q fragments (B-operand: n=s, k=dh), persist whole kernel
    short8 qf[2][2];
#pragma unroll
    for (int ns = 0; ns < 2; ++ns)
#pragma unroll
        for (int kk = 0; kk < 2; ++kk)
            qf[ns][kk] = *(const short8*)&q[(size_t)(s0 + sw + ns * 16 + lm) * LQ + kk * 32 + quad * 8];

    // glds staging geometry: wave stages tile rows [16w..16w+15] (2 instrs each for K, VT)
    const int lr  = lane >> 3;            // 0..7
    const int lc  = lane & 7;             // chunk position in LDS
    const int gch = lc ^ lr;              // swizzled global chunk
    const u16* kg0 = kg + (size_t)(16 * wave + lr) * LQ + gch * 8;   // + t*LQ per tile
    const u16* vg0 = vt + (size_t)(16 * wave + lr) * S_ + gch * 8;   // + t per tile
    // fragment-read swizzled chunk offsets (loop-invariant)
    const int cof0 = ((0 * 4 + quad) ^ (lm & 7)) * 8;   // kk=0
    const int cof1 = ((1 * 4 + quad) ^ (lm & 7)) * 8;   // kk=1

#define GLDS(gp, lp) __builtin_amdgcn_global_load_lds( \
        (const __attribute__((address_space(1))) void*)(gp), \
        (__attribute__((address_space(3))) void*)(lp), 16, 0, 0)

    // pre-stage tile 0 into buf 0
    GLDS(kg0,                     &Ks[0][(16 * wave) * 64]);
    GLDS(kg0 + (size_t)8 * LQ,    &Ks[0][(16 * wave + 8) * 64]);
    GLDS(vg0,                     &Vs[0][(16 * wave) * 64]);
    GLDS(vg0 + (size_t)8 * S_,    &Vs[0][(16 * wave + 8) * 64]);

    f32x4 accO[2][4] = {};
    __syncthreads();   // tile 0 + pbl visible

    for (int t0 = 0; t0 < S_; t0 += 64) {
        const int ib = (t0 >> 6) & 1;
        const int nb = ib ^ 1;
        if (t0 + 64 < S_) {
            const size_t tn = (size_t)(t0 + 64);
            GLDS(kg0 + tn * LQ,            &Ks[nb][(16 * wave) * 64]);
            GLDS(kg0 + (tn + 8) * LQ,      &Ks[nb][(16 * wave + 8) * 64]);
            GLDS(vg0 + tn,                 &Vs[nb][(16 * wave) * 64]);
            GLDS(vg0 + tn + (size_t)8 * S_,&Vs[nb][(16 * wave + 8) * 64]);
        }
        // K fragments from LDS
        short8 kf[4][2];
#pragma unroll
        for (int mt = 0; mt < 4; ++mt) {
            kf[mt][0] = *(const short8*)&Ks[ib][(mt * 16 + lm) * 64 + cof0];
            kf[mt][1] = *(const short8*)&Ks[ib][(mt * 16 + lm) * 64 + cof1];
        }
        // S^T = K @ Q^T
        f32x4 st[4][2] = {};
#pragma unroll
        for (int mt = 0; mt < 4; ++mt)
#pragma unroll
            for (int ns = 0; ns < 2; ++ns)
#pragma unroll
                for (int kk = 0; kk < 2; ++kk)
                    st[mt][ns] = __builtin_amdgcn_mfma_f32_16x16x32_bf16(kf[mt][kk], qf[ns][kk], st[mt][ns], 0, 0, 0);
        // P = silu(0.125*S + pb) -> per-wave Pl rows (intra-wave LDS, no barrier)
#pragma unroll
        for (int mt = 0; mt < 4; ++mt) {
            const int tl = mt * 16 + quad * 4;
            float4 pbv = *(const float4*)&pbl[t0 + tl];
#pragma unroll
            for (int ns = 0; ns < 2; ++ns) {
                const float e0 = silu_f(fmaf(st[mt][ns][0], 0.125f, pbv.x));
                const float e1 = silu_f(fmaf(st[mt][ns][1], 0.125f, pbv.y));
                const float e2 = silu_f(fmaf(st[mt][ns][2], 0.125f, pbv.z));
                const float e3 = silu_f(fmaf(st[mt][ns][3], 0.125f, pbv.w));
                uint2 pk;
                pk.x = pack2bf(e0, e1);
                pk.y = pack2bf(e2, e3);
                *(uint2*)&Pl[(sw + ns * 16 + lm) * 72 + tl] = pk;
            }
        }
        // fragments for PV (P: own-wave rows; V: swizzled tile)
        short8 pf[2][2], vf[4][2];
#pragma unroll
        for (int mi = 0; mi < 2; ++mi)
#pragma unroll
            for (int kk = 0; kk < 2; ++kk)
                pf[mi][kk] = *(const short8*)&Pl[(sw + mi * 16 + lm) * 72 + kk * 32 + quad * 8];
#pragma unroll
        for (int nj = 0; nj < 4; ++nj) {
            vf[nj][0] = *(const short8*)&Vs[ib][(nj * 16 + lm) * 64 + cof0];
            vf[nj][1] = *(const short8*)&Vs[ib][(nj * 16 + lm) * 64 + cof1];
        }
#pragma unroll
        for (int mi = 0; mi < 2; ++mi)
#pragma unroll
            for (int nj = 0; nj < 4; ++nj)
#pragma unroll
                for (int kk = 0; kk < 2; ++kk)
                    accO[mi][nj] = __builtin_amdgcn_mfma_f32_16x16x32_bf16(pf[mi][kk], vf[nj][kk], accO[mi][nj], 0, 0, 0);
        __syncthreads();   // protects Ks/Vs double buffers (this iter's glds drained)
    }
#undef GLDS
    // store O: col=dh=nj*16+lm, row=s
#pragma unroll
    for (int mi = 0; mi < 2; ++mi)
#pragma unroll
        for (int nj = 0; nj < 4; ++nj)
#pragma unroll
            for (int r = 0; r < 4; ++r) {
                const int s = s0 + sw + mi * 16 + quad * 4 + r;
                out[base + (size_t)s * LQ + nj * 16 + lm] = f2bf(accO[mi][nj][r]);
            }
}

// ---------------- SwiGLU on QKVU: x1=cols[0,1024), x2=[1024,2048) -> [2048,3072) ----
__global__ __launch_bounds__(256) void swiglu_kernel(u16* __restrict__ qkvu)
{
    const size_t e = ((size_t)blockIdx.x * 256 + threadIdx.x) << 2;
    const size_t r = e >> 10;
    const int    c = (int)(e & 1023);
    ushort4 a = *(const ushort4*)&qkvu[r * LQ + c];
    ushort4 b = *(const ushort4*)&qkvu[r * LQ + 1024 + c];
    ushort4 o;
    o.x = f2bf(silu_f(bf2f(a.x)) * bf2f(b.x));
    o.y = f2bf(silu_f(bf2f(a.y)) * bf2f(b.y));
    o.z = f2bf(silu_f(bf2f(a.z)) * bf2f(b.z));
    o.w = f2bf(silu_f(bf2f(a.w)) * bf2f(b.w));
    *(ushort4*)&qkvu[r * LQ + 2048 + c] = o;
}

extern "C" void kernel_launch(void* const* d_in, const int* in_sizes, int n_in,
                              void* d_out, int out_size, void* d_ws, size_t ws_size,
                              hipStream_t stream)
{
    const float* x      = (const float*)d_in[0];
    const float* pb     = (const float*)d_in[2];
    const float* wq     = (const float*)d_in[3];
    const float* bq     = (const float*)d_in[4];
    const float* wk     = (const float*)d_in[5];
    const float* bk     = (const float*)d_in[6];
    const float* wv     = (const float*)d_in[7];
    const float* bv     = (const float*)d_in[8];
    const float* wu     = (const float*)d_in[9];
    const float* bu     = (const float*)d_in[10];
    const float* g_ams  = (const float*)d_in[11];
    const float* w0     = (const float*)d_in[12];
    const float* b0     = (const float*)d_in[13];
    const float* w1     = (const float*)d_in[14];
    const float* b1     = (const float*)d_in[15];
    const float* w2     = (const float*)d_in[16];
    const float* b2     = (const float*)d_in[17];
    const float* g_mffn = (const float*)d_in[18];
    float* OUT = (float*)d_out;
    u16*   VT  = (u16*)d_out;              // VT[b][h][64][2048] (8 MB) — dead after attn,
                                           // fully overwritten by o (16 MB) in step 5.

    const size_t MI = 1024 * 1024;
    u16* WS   = (u16*)d_ws;                // 56 MB total
    u16* wT4  = WS;                        // [4096][1024] stacked wq|wk|wv|wu
    u16* w0T  = WS + 4 * MI;
    u16* w2T  = WS + 5 * MI;
    u16* w1T  = WS + 6 * MI;               // [2048][1024]
    u16* A0   = WS + 8 * MI;               // [4096][1024] bf16
    u16* QKVU = WS + 12 * MI;              // [4096][4096] bf16

    dim3 blk(256);

    // 0. all weight transposes, one dispatch
    transpose_all_kernel<<<dim3(16, 16, 8), blk, 0, stream>>>(
        wq, wk, wv, wu, w0, w2, w1, wT4, w0T, w2T, w1T);

    // 1. xn = rmsnorm(x)*g_ams -> A0
    rmsnorm_kernel<<<ROWS, blk, 0, stream>>>(x, nullptr, D, g_ams, nullptr, 0, A0, D);
    // 2. QKVU = xn @ [wq|wk|wv|wu] (+bias, silu on u); v-chunk -> VT transposed
    gemm128<<<dim3(32, 32), blk, 0, stream>>>(A0, wT4, bq, bk, bv, bu,
                                              QKVU, LQ, 0b1000, VT, 2);
    // 3. attention (K from QKVU, V from VT) -> q-slot (in-place)
    attn_mfma<<<dim3(S_ / 128, NH, B_), blk, 0, stream>>>(QKVU, VT, pb, QKVU);
    // 4. ams = rmsnorm(attn)*g_ams*u -> A0 (xn dead)
    rmsnorm_kernel<<<ROWS, blk, 0, stream>>>(nullptr, QKVU, LQ, g_ams, QKVU + 3072, LQ, A0, D);
    // 5. o = ams@w0 + b0 + x -> OUT fp32 (overwrites VT region)
    gemm64<<<dim3(16, 32), blk, 0, stream>>>(A0, D, w0T, b0, x, OUT, D);
    // 6. o_norm = rmsnorm(o)*g_mffn -> A0 (ams dead)
    rmsnorm_kernel<<<ROWS, blk, 0, stream>>>(OUT, nullptr, D, g_mffn, nullptr, 0, A0, D);
    // 7. x12 = o_norm@w1 + b1 -> QKVU cols[0,2048)
    gemm128<<<dim3(16, 32), blk, 0, stream>>>(A0, w1T, b1, b1 + 1024, b1, b1,
                                              QKVU, LQ, 0, nullptr, -1);
    // 8. swiglu -> QKVU cols[2048,3072)
    swiglu_kernel<<<ROWS * D / 1024, blk, 0, stream>>>(QKVU);
    // 9. out = swiglu@w2 + b2 + o -> OUT (in-place residual)
    gemm64<<<dim3(16, 32), blk, 0, stream>>>(QKVU + 2048, LQ, w2T, b2, OUT, OUT, D);
    (void)ws_size; (void)in_sizes; (void)n_in; (void)out_size;
}

// Round 9
// 350.132 us; speedup vs baseline: 1.4329x; 1.0943x over previous
//
#include <hip/hip_runtime.h>
#include <stdint.h>
#include <math.h>

// FuXi block on MI355X, round 9: silu-VALU round.
// r8 post-mortem: attn is VALU-issue-bound on silu — x/(1+exp(-x)) compiles to the
// full IEEE divide (~60 cyc/elem) without fast-math. Replace with
// x * v_rcp(1 + v_exp2(x * -log2e)) (~24 cyc/elem), -log2e folded into the pb bias.
// Structure identical to round 8 otherwise (isolate the variable).

#define D    1024
#define NH   16
#define DH   64
#define B_   2
#define S_   2048
#define ROWS 4096
#define LQ   4096          // QKVU row stride
#define EPSR 1e-8f

typedef unsigned short u16;
typedef __attribute__((ext_vector_type(8))) short short8;
typedef __attribute__((ext_vector_type(4))) float f32x4;

__device__ __forceinline__ float bf2f(u16 u) {
    union { uint32_t i; float f; } c; c.i = ((uint32_t)u) << 16; return c.f;
}
__device__ __forceinline__ u16 f2bf(float f) {
    union { float f; uint32_t i; } c; c.f = f;
    uint32_t x = c.i;
    x += 0x7fffu + ((x >> 16) & 1u);
    return (u16)(x >> 16);
}
// pack two f32 -> (bf16(a) | bf16(b)<<16), round-half-up via +0x8000 then v_perm
__device__ __forceinline__ uint32_t pack2bf(float a, float b) {
    union { float f; uint32_t i; } ca, cb; ca.f = a; cb.f = b;
    return __builtin_amdgcn_perm(cb.i + 0x8000u, ca.i + 0x8000u, 0x07060302);
}
#define LOG2E 1.44269504f
// fast silu: one v_exp (=2^x) + one v_rcp, no IEEE divide
__device__ __forceinline__ float silu_fast(float v) {
    return v * __builtin_amdgcn_rcpf(1.0f + __builtin_amdgcn_exp2f(v * -LOG2E));
}

// ---------------- fused weight prep: 7 transposes in one dispatch ----------------
__global__ __launch_bounds__(256) void transpose_all_kernel(
    const float* __restrict__ wq, const float* __restrict__ wk,
    const float* __restrict__ wv, const float* __restrict__ wu,
    const float* __restrict__ w0, const float* __restrict__ w2,
    const float* __restrict__ w1,
    u16* __restrict__ wT4, u16* __restrict__ w0T,
    u16* __restrict__ w2T, u16* __restrict__ w1T)
{
    const unsigned MI = 1u << 20;
    const int z = blockIdx.z;
    const float* W; u16* WT; int N; int noff = 0;
    switch (z) {
        case 0: W = wq; WT = wT4;          N = 1024; break;
        case 1: W = wk; WT = wT4 + 1 * MI; N = 1024; break;
        case 2: W = wv; WT = wT4 + 2 * MI; N = 1024; break;
        case 3: W = wu; WT = wT4 + 3 * MI; N = 1024; break;
        case 4: W = w0; WT = w0T;          N = 1024; break;
        case 5: W = w2; WT = w2T;          N = 1024; break;
        case 6: W = w1; WT = w1T;          N = 2048; noff = 0;    break;
        default:W = w1; WT = w1T;          N = 2048; noff = 1024; break;
    }
    __shared__ float T[64][65];
    const int tid = threadIdx.x;
    const int n0 = (blockIdx.x << 6) + noff;
    const int k0 = blockIdx.y << 6;
    const int rr = tid >> 4;
    const int cc = (tid & 15) << 2;
#pragma unroll
    for (int l = 0; l < 4; ++l) {
        const int r = rr + (l << 4);
        float4 v = *(const float4*)&W[(size_t)(k0 + r) * N + n0 + cc];
        T[cc + 0][r] = v.x; T[cc + 1][r] = v.y;
        T[cc + 2][r] = v.z; T[cc + 3][r] = v.w;
    }
    __syncthreads();
    const int n  = tid >> 2;
    const int ks = (tid & 3) << 4;
#pragma unroll
    for (int m = 0; m < 4; ++m) {
        const int k = ks + (m << 2);
        float4 v = *(const float4*)&T[n][k];
        ushort4 o;
        o.x = f2bf(v.x); o.y = f2bf(v.y); o.z = f2bf(v.z); o.w = f2bf(v.w);
        *(ushort4*)&WT[(size_t)(n0 + n) * 1024 + k0 + k] = o;
    }
}

// ---------------- RMSNorm ----------------
__global__ __launch_bounds__(256) void rmsnorm_kernel(
    const float* __restrict__ inf, const u16* __restrict__ inb, int ldi,
    const float* __restrict__ g,
    const u16* __restrict__ mul, int ldm,
    u16* __restrict__ out, int ldo)
{
    const int row = blockIdx.x;
    const int tid = threadIdx.x;
    const int c = tid << 2;
    float x0, x1, x2, x3;
    if (inb) {
        ushort4 xi = *(const ushort4*)&inb[(size_t)row * ldi + c];
        x0 = bf2f(xi.x); x1 = bf2f(xi.y); x2 = bf2f(xi.z); x3 = bf2f(xi.w);
    } else {
        float4 xi = *(const float4*)&inf[(size_t)row * ldi + c];
        x0 = xi.x; x1 = xi.y; x2 = xi.z; x3 = xi.w;
    }
    float ss = x0*x0 + x1*x1 + x2*x2 + x3*x3;
#pragma unroll
    for (int off = 32; off > 0; off >>= 1) ss += __shfl_down(ss, off, 64);
    __shared__ float red[4];
    if ((tid & 63) == 0) red[tid >> 6] = ss;
    __syncthreads();
    float r = rsqrtf((red[0] + red[1] + red[2] + red[3]) * (1.0f / D) + EPSR);
    float4 gv = *(const float4*)&g[c];
    float v0 = x0 * r * gv.x, v1 = x1 * r * gv.y, v2 = x2 * r * gv.z, v3 = x3 * r * gv.w;
    if (mul) {
        ushort4 mi = *(const ushort4*)&mul[(size_t)row * ldm + c];
        v0 *= bf2f(mi.x); v1 *= bf2f(mi.y); v2 *= bf2f(mi.z); v3 *= bf2f(mi.w);
    }
    ushort4 o;
    o.x = f2bf(v0); o.y = f2bf(v1); o.z = f2bf(v2); o.w = f2bf(v3);
    *(ushort4*)&out[(size_t)row * ldo + c] = o;
}

// ---------------- 128x128 MFMA GEMM (m97 motif), bf16 out ----------------
__global__ __launch_bounds__(256) void gemm128(
    const u16* __restrict__ A, const u16* __restrict__ WT,
    const float* __restrict__ bs0, const float* __restrict__ bs1,
    const float* __restrict__ bs2, const float* __restrict__ bs3,
    u16* __restrict__ outb, int ldo, int actmask,
    u16* __restrict__ VT, int vtsel)
{
    __shared__ u16 As[128 * 32];
    __shared__ u16 Bs[128 * 32];
    const int tid  = threadIdx.x;
    const int wave = tid >> 6;
    const int lane = tid & 63;
    const int lm   = lane & 15;
    const int quad = lane >> 4;
    const int row0 = blockIdx.y << 7;
    const int col0 = blockIdx.x << 7;
    const int wr = (wave >> 1) << 6;
    const int wc = (wave & 1) << 6;

    const int srow = wave * 32 + (lane >> 2);
    const int skp  = (lane & 3) << 3;
    const u16* Ag = A  + (size_t)(row0 + srow) * 1024 + skp;
    const u16* Bg = WT + (size_t)(col0 + srow) * 1024 + skp;
    u16* Asd0 = &As[(wave * 32) * 32];
    u16* Asd1 = &As[(wave * 32 + 16) * 32];
    u16* Bsd0 = &Bs[(wave * 32) * 32];
    u16* Bsd1 = &Bs[(wave * 32 + 16) * 32];

    f32x4 acc[4][4] = {};

    for (int k0 = 0; k0 < 1024; k0 += 32) {
        __syncthreads();
        __builtin_amdgcn_global_load_lds(
            (const __attribute__((address_space(1))) void*)(Ag + k0),
            (__attribute__((address_space(3))) void*)Asd0, 16, 0, 0);
        __builtin_amdgcn_global_load_lds(
            (const __attribute__((address_space(1))) void*)(Ag + 16 * 1024 + k0),
            (__attribute__((address_space(3))) void*)Asd1, 16, 0, 0);
        __builtin_amdgcn_global_load_lds(
            (const __attribute__((address_space(1))) void*)(Bg + k0),
            (__attribute__((address_space(3))) void*)Bsd0, 16, 0, 0);
        __builtin_amdgcn_global_load_lds(
            (const __attribute__((address_space(1))) void*)(Bg + 16 * 1024 + k0),
            (__attribute__((address_space(3))) void*)Bsd1, 16, 0, 0);
        __syncthreads();
        short8 af[4], bf[4];
#pragma unroll
        for (int i = 0; i < 4; ++i)
            af[i] = *(const short8*)&As[(wr + i * 16 + lm) * 32 + quad * 8];
#pragma unroll
        for (int j = 0; j < 4; ++j)
            bf[j] = *(const short8*)&Bs[(wc + j * 16 + lm) * 32 + quad * 8];
#pragma unroll
        for (int i = 0; i < 4; ++i)
#pragma unroll
            for (int j = 0; j < 4; ++j)
                acc[i][j] = __builtin_amdgcn_mfma_f32_16x16x32_bf16(af[i], bf[j], acc[i][j], 0, 0, 0);
    }
    const int sel = col0 >> 10;
    const float* bias = (sel == 0) ? bs0 : (sel == 1) ? bs1 : (sel == 2) ? bs2 : bs3;
    const int act = (actmask >> sel) & 1;
    if (VT && sel == vtsel) {
        // transposed write: VT[b][h][dh][t], t-consecutive regs -> ushort4 stores
        const int b = row0 >> 11;
#pragma unroll
        for (int j = 0; j < 4; ++j) {
            const int c2 = (col0 + wc + j * 16 + lm) & 1023;
            const int h  = c2 >> 6;
            const int dh = c2 & 63;
            const float bj = bias[c2];
            u16* vrow = VT + ((size_t)(b * NH + h) * 64 + dh) * (size_t)S_;
#pragma unroll
            for (int i = 0; i < 4; ++i) {
                const int tb = (row0 & 2047) + wr + i * 16 + quad * 4;
                ushort4 o;
                o.x = f2bf(acc[i][j][0] + bj);
                o.y = f2bf(acc[i][j][1] + bj);
                o.z = f2bf(acc[i][j][2] + bj);
                o.w = f2bf(acc[i][j][3] + bj);
                *(ushort4*)&vrow[tb] = o;
            }
        }
    } else {
#pragma unroll
        for (int j = 0; j < 4; ++j) {
            const int colg = col0 + wc + j * 16 + lm;
            const float bj = bias[colg & 1023];
#pragma unroll
            for (int i = 0; i < 4; ++i) {
#pragma unroll
                for (int r = 0; r < 4; ++r) {
                    const int rowg = row0 + wr + i * 16 + quad * 4 + r;
                    float v = acc[i][j][r] + bj;
                    if (act) v = silu_fast(v);
                    outb[(size_t)rowg * ldo + colg] = f2bf(v);
                }
            }
        }
    }
}

// ---------------- 128x64 MFMA GEMM (for N=1024: w0, w2) ----------------
__global__ __launch_bounds__(256) void gemm64(
    const u16* __restrict__ A, int lda, const u16* __restrict__ WT,
    const float* __restrict__ bias,
    const float* __restrict__ res,
    float* __restrict__ outf, int ldo)
{
    __shared__ u16 As[128 * 32];
    __shared__ u16 Bs[64 * 32];
    const int tid  = threadIdx.x;
    const int wave = tid >> 6;
    const int lane = tid & 63;
    const int lm   = lane & 15;
    const int quad = lane >> 4;
    const int row0 = blockIdx.y << 7;
    const int col0 = blockIdx.x << 6;
    const int wr = (wave >> 1) << 6;
    const int wc = (wave & 1) << 5;

    const int srA = wave * 32 + (lane >> 2);
    const int srB = wave * 16 + (lane >> 2);
    const int skp = (lane & 3) << 3;
    const u16* Ag = A  + (size_t)(row0 + srA) * lda + skp;
    const u16* Bg = WT + (size_t)(col0 + srB) * 1024 + skp;
    u16* Asd0 = &As[(wave * 32) * 32];
    u16* Asd1 = &As[(wave * 32 + 16) * 32];
    u16* Bsd  = &Bs[(wave * 16) * 32];

    f32x4 acc[4][2] = {};

    for (int k0 = 0; k0 < 1024; k0 += 32) {
        __syncthreads();
        __builtin_amdgcn_global_load_lds(
            (const __attribute__((address_space(1))) void*)(Ag + k0),
            (__attribute__((address_space(3))) void*)Asd0, 16, 0, 0);
        __builtin_amdgcn_global_load_lds(
            (const __attribute__((address_space(1))) void*)(Ag + (size_t)16 * lda + k0),
            (__attribute__((address_space(3))) void*)Asd1, 16, 0, 0);
        __builtin_amdgcn_global_load_lds(
            (const __attribute__((address_space(1))) void*)(Bg + k0),
            (__attribute__((address_space(3))) void*)Bsd, 16, 0, 0);
        __syncthreads();
        short8 af[4], bf[2];
#pragma unroll
        for (int i = 0; i < 4; ++i)
            af[i] = *(const short8*)&As[(wr + i * 16 + lm) * 32 + quad * 8];
#pragma unroll
        for (int j = 0; j < 2; ++j)
            bf[j] = *(const short8*)&Bs[(wc + j * 16 + lm) * 32 + quad * 8];
#pragma unroll
        for (int i = 0; i < 4; ++i)
#pragma unroll
            for (int j = 0; j < 2; ++j)
                acc[i][j] = __builtin_amdgcn_mfma_f32_16x16x32_bf16(af[i], bf[j], acc[i][j], 0, 0, 0);
    }
#pragma unroll
    for (int j = 0; j < 2; ++j) {
        const int colg = col0 + wc + j * 16 + lm;
        const float bj = bias[colg];
#pragma unroll
        for (int i = 0; i < 4; ++i) {
#pragma unroll
            for (int r = 0; r < 4; ++r) {
                const int rowg = row0 + wr + i * 16 + quad * 4 + r;
                const size_t idx = (size_t)rowg * ldo + colg;
                float v = acc[i][j][r] + bj;
                if (res) v += res[idx];
                outf[idx] = v;
            }
        }
    }
}

// ---------------- MFMA SiLU attention, glds-staged tiles, fast silu ----------------
__global__ __launch_bounds__(256) void attn_mfma(
    const u16* __restrict__ qkvu, const u16* __restrict__ VT,
    const float* __restrict__ pb, u16* __restrict__ out)
{
    __shared__ u16 Ks[2][64 * 64];
    __shared__ u16 Vs[2][64 * 64];
    __shared__ u16 Pl[128 * 72];
    __shared__ float pbl[S_];
    const int tid  = threadIdx.x;
    const int wave = tid >> 6;
    const int lane = tid & 63;
    const int lm   = lane & 15;
    const int quad = lane >> 4;
    const int s0 = blockIdx.x << 7;
    const int h  = blockIdx.y;
    const int b  = blockIdx.z;
    const size_t base = (size_t)b * S_ * LQ + (size_t)h * DH;
    const u16* q  = qkvu + base;
    const u16* kg = qkvu + base + 1024;
    const u16* vt = VT + (size_t)(b * NH + h) * 64 * S_;
    const int sw = wave << 5;

    for (int i = tid; i < S_; i += 256) pbl[i] = pb[(size_t)i * NH + h];

    short8 qf[2][2];
#pragma unroll
    for (int ns = 0; ns < 2; ++ns)
#pragma unroll
        for (int kk = 0; kk < 2; ++kk)
            qf[ns][kk] = *(const short8*)&q[(size_t)(s0 + sw + ns * 16 + lm) * LQ + kk * 32 + quad * 8];

    const int lr  = lane >> 3;
    const int lc  = lane & 7;
    const int gch = lc ^ lr;
    const u16* kg0 = kg + (size_t)(16 * wave + lr) * LQ + gch * 8;
    const u16* vg0 = vt + (size_t)(16 * wave + lr) * S_ + gch * 8;
    const int cof0 = ((0 * 4 + quad) ^ (lm & 7)) * 8;
    const int cof1 = ((1 * 4 + quad) ^ (lm & 7)) * 8;

#define GLDS(gp, lp) __builtin_amdgcn_global_load_lds( \
        (const __attribute__((address_space(1))) void*)(gp), \
        (__attribute__((address_space(3))) void*)(lp), 16, 0, 0)

    GLDS(kg0,                     &Ks[0][(16 * wave) * 64]);
    GLDS(kg0 + (size_t)8 * LQ,    &Ks[0][(16 * wave + 8) * 64]);
    GLDS(vg0,                     &Vs[0][(16 * wave) * 64]);
    GLDS(vg0 + (size_t)8 * S_,    &Vs[0][(16 * wave + 8) * 64]);

    f32x4 accO[2][4] = {};
    __syncthreads();

    for (int t0 = 0; t0 < S_; t0 += 64) {
        const int ib = (t0 >> 6) & 1;
        const int nb = ib ^ 1;
        if (t0 + 64 < S_) {
            const size_t tn = (size_t)(t0 + 64);
            GLDS(kg0 + tn * LQ,            &Ks[nb][(16 * wave) * 64]);
            GLDS(kg0 + (tn + 8) * LQ,      &Ks[nb][(16 * wave + 8) * 64]);
            GLDS(vg0 + tn,                 &Vs[nb][(16 * wave) * 64]);
            GLDS(vg0 + tn + (size_t)8 * S_,&Vs[nb][(16 * wave + 8) * 64]);
        }
        short8 kf[4][2];
#pragma unroll
        for (int mt = 0; mt < 4; ++mt) {
            kf[mt][0] = *(const short8*)&Ks[ib][(mt * 16 + lm) * 64 + cof0];
            kf[mt][1] = *(const short8*)&Ks[ib][(mt * 16 + lm) * 64 + cof1];
        }
        f32x4 st[4][2] = {};
#pragma unroll
        for (int mt = 0; mt < 4; ++mt)
#pragma unroll
            for (int ns = 0; ns < 2; ++ns)
#pragma unroll
                for (int kk = 0; kk < 2; ++kk)
                    st[mt][ns] = __builtin_amdgcn_mfma_f32_16x16x32_bf16(kf[mt][kk], qf[ns][kk], st[mt][ns], 0, 0, 0);
        // P = silu(0.125*S + pb): fast path — a = fma(st,.125,pb);
        // e = exp2(fma(st,-.125*log2e, pb*-log2e)); p = a*rcp(1+e)
#pragma unroll
        for (int mt = 0; mt < 4; ++mt) {
            const int tl = mt * 16 + quad * 4;
            float4 pbv = *(const float4*)&pbl[t0 + tl];
            const float pbr[4]  = {pbv.x, pbv.y, pbv.z, pbv.w};
            const float pbr2[4] = {pbv.x * -LOG2E, pbv.y * -LOG2E,
                                   pbv.z * -LOG2E, pbv.w * -LOG2E};
#pragma unroll
            for (int ns = 0; ns < 2; ++ns) {
                float p[4];
#pragma unroll
                for (int r = 0; r < 4; ++r) {
                    const float a = fmaf(st[mt][ns][r], 0.125f, pbr[r]);
                    const float e = __builtin_amdgcn_exp2f(
                        fmaf(st[mt][ns][r], -0.125f * LOG2E, pbr2[r]));
                    p[r] = a * __builtin_amdgcn_rcpf(1.0f + e);
                }
                uint2 pk;
                pk.x = pack2bf(p[0], p[1]);
                pk.y = pack2bf(p[2], p[3]);
                *(uint2*)&Pl[(sw + ns * 16 + lm) * 72 + tl] = pk;
            }
        }
        short8 pf[2][2], vf[4][2];
#pragma unroll
        for (int mi = 0; mi < 2; ++mi)
#pragma unroll
            for (int kk = 0; kk < 2; ++kk)
                pf[mi][kk] = *(const short8*)&Pl[(sw + mi * 16 + lm) * 72 + kk * 32 + quad * 8];
#pragma unroll
        for (int nj = 0; nj < 4; ++nj) {
            vf[nj][0] = *(const short8*)&Vs[ib][(nj * 16 + lm) * 64 + cof0];
            vf[nj][1] = *(const short8*)&Vs[ib][(nj * 16 + lm) * 64 + cof1];
        }
#pragma unroll
        for (int mi = 0; mi < 2; ++mi)
#pragma unroll
            for (int nj = 0; nj < 4; ++nj)
#pragma unroll
                for (int kk = 0; kk < 2; ++kk)
                    accO[mi][nj] = __builtin_amdgcn_mfma_f32_16x16x32_bf16(pf[mi][kk], vf[nj][kk], accO[mi][nj], 0, 0, 0);
        __syncthreads();
    }
#undef GLDS
#pragma unroll
    for (int mi = 0; mi < 2; ++mi)
#pragma unroll
        for (int nj = 0; nj < 4; ++nj)
#pragma unroll
            for (int r = 0; r < 4; ++r) {
                const int s = s0 + sw + mi * 16 + quad * 4 + r;
                out[base + (size_t)s * LQ + nj * 16 + lm] = f2bf(accO[mi][nj][r]);
            }
}

// ---------------- SwiGLU on QKVU: x1=cols[0,1024), x2=[1024,2048) -> [2048,3072) ----
__global__ __launch_bounds__(256) void swiglu_kernel(u16* __restrict__ qkvu)
{
    const size_t e = ((size_t)blockIdx.x * 256 + threadIdx.x) << 2;
    const size_t r = e >> 10;
    const int    c = (int)(e & 1023);
    ushort4 a = *(const ushort4*)&qkvu[r * LQ + c];
    ushort4 b = *(const ushort4*)&qkvu[r * LQ + 1024 + c];
    ushort4 o;
    o.x = f2bf(silu_fast(bf2f(a.x)) * bf2f(b.x));
    o.y = f2bf(silu_fast(bf2f(a.y)) * bf2f(b.y));
    o.z = f2bf(silu_fast(bf2f(a.z)) * bf2f(b.z));
    o.w = f2bf(silu_fast(bf2f(a.w)) * bf2f(b.w));
    *(ushort4*)&qkvu[r * LQ + 2048 + c] = o;
}

extern "C" void kernel_launch(void* const* d_in, const int* in_sizes, int n_in,
                              void* d_out, int out_size, void* d_ws, size_t ws_size,
                              hipStream_t stream)
{
    const float* x      = (const float*)d_in[0];
    const float* pb     = (const float*)d_in[2];
    const float* wq     = (const float*)d_in[3];
    const float* bq     = (const float*)d_in[4];
    const float* wk     = (const float*)d_in[5];
    const float* bk     = (const float*)d_in[6];
    const float* wv     = (const float*)d_in[7];
    const float* bv     = (const float*)d_in[8];
    const float* wu     = (const float*)d_in[9];
    const float* bu     = (const float*)d_in[10];
    const float* g_ams  = (const float*)d_in[11];
    const float* w0     = (const float*)d_in[12];
    const float* b0     = (const float*)d_in[13];
    const float* w1     = (const float*)d_in[14];
    const float* b1     = (const float*)d_in[15];
    const float* w2     = (const float*)d_in[16];
    const float* b2     = (const float*)d_in[17];
    const float* g_mffn = (const float*)d_in[18];
    float* OUT = (float*)d_out;
    u16*   VT  = (u16*)d_out;              // VT[b][h][64][2048] (8 MB) — dead after attn

    const size_t MI = 1024 * 1024;
    u16* WS   = (u16*)d_ws;                // 56 MB total
    u16* wT4  = WS;
    u16* w0T  = WS + 4 * MI;
    u16* w2T  = WS + 5 * MI;
    u16* w1T  = WS + 6 * MI;
    u16* A0   = WS + 8 * MI;
    u16* QKVU = WS + 12 * MI;

    dim3 blk(256);

    transpose_all_kernel<<<dim3(16, 16, 8), blk, 0, stream>>>(
        wq, wk, wv, wu, w0, w2, w1, wT4, w0T, w2T, w1T);

    rmsnorm_kernel<<<ROWS, blk, 0, stream>>>(x, nullptr, D, g_ams, nullptr, 0, A0, D);
    gemm128<<<dim3(32, 32), blk, 0, stream>>>(A0, wT4, bq, bk, bv, bu,
                                              QKVU, LQ, 0b1000, VT, 2);
    attn_mfma<<<dim3(S_ / 128, NH, B_), blk, 0, stream>>>(QKVU, VT, pb, QKVU);
    rmsnorm_kernel<<<ROWS, blk, 0, stream>>>(nullptr, QKVU, LQ, g_ams, QKVU + 3072, LQ, A0, D);
    gemm64<<<dim3(16, 32), blk, 0, stream>>>(A0, D, w0T, b0, x, OUT, D);
    rmsnorm_kernel<<<ROWS, blk, 0, stream>>>(OUT, nullptr, D, g_mffn, nullptr, 0, A0, D);
    gemm128<<<dim3(16, 32), blk, 0, stream>>>(A0, w1T, b1, b1 + 1024, b1, b1,
                                              QKVU, LQ, 0, nullptr, -1);
    swiglu_kernel<<<ROWS * D / 1024, blk, 0, stream>>>(QKVU);
    gemm64<<<dim3(16, 32), blk, 0, stream>>>(QKVU + 2048, LQ, w2T, b2, OUT, OUT, D);
    (void)ws_size; (void)in_sizes; (void)n_in; (void)out_size;
}